// Round 8
// baseline (560.130 us; speedup 1.0000x reference)
//
#include <hip/hip_runtime.h>
#include <hip/hip_bf16.h>

typedef __attribute__((ext_vector_type(8))) short short8x;   // 8 x bf16 (4 VGPR) MFMA A/B frag
typedef __attribute__((ext_vector_type(4))) float f32x4;     // MFMA C/D frag

__device__ __forceinline__ ushort f2bf(float f){
  union { __hip_bfloat16 b; ushort u; } cvt;
  cvt.b = __float2bfloat16(f);                // RNE
  return cvt.u;
}

// ---------------- elementwise fp32 -> bf16 (optional scale) ----------------
__global__ __launch_bounds__(256) void cvt_kernel(const float* __restrict__ in, ushort* __restrict__ out,
                                                  long n, float scale){
  long i = ((long)blockIdx.x * 256 + threadIdx.x) * 4;
  if (i >= n) return;
  float4 v = *(const float4*)(in + i);
  ushort4 o;
  o.x = f2bf(v.x * scale); o.y = f2bf(v.y * scale); o.z = f2bf(v.z * scale); o.w = f2bf(v.w * scale);
  *(ushort4*)(out + i) = o;
}

// ---------------- generic bf16 GEMM: C = A[M,K] * B  with B given as BT[N,K] ----------------
// 128x128 tile, BK=32, 4 waves (2x2), double-buffered LDS staged via global_load_lds(16B).
// XCD-aware block swizzle (T1): all launches have (gridDim.x*gridDim.y) % 8 == 0.
template<int OUTBF>
__global__ __launch_bounds__(256, 3)
void gemm_bt(const ushort* __restrict__ A, const ushort* __restrict__ BT, void* __restrict__ Cv,
             int M, int N, int K, int lda, int ldb, int ldc,
             long aZ, long bZ, long cZ, float scale)
{
  __shared__ __align__(16) ushort As[2][128 * 32];
  __shared__ __align__(16) ushort Bs[2][128 * 32];
  const int z = blockIdx.z;
  const ushort* Ab = A + (long)z * aZ;
  const ushort* Bb = BT + (long)z * bZ;
  const int tid = threadIdx.x, lane = tid & 63, w = tid >> 6;
  const int wm = w >> 1, wn = w & 1;
  const int lq = lane & 15, q4 = lane >> 4;

  int lin = blockIdx.x + gridDim.x * blockIdx.y;
  const int cpx = (gridDim.x * gridDim.y) >> 3;
  lin = (lin & 7) * cpx + (lin >> 3);
  const int bx = lin % gridDim.x, by = lin / gridDim.x;

  const long arow = (long)by * 128, brow = (long)bx * 128;
  const int lr = lane >> 2, lc = (lane & 3) * 8;

  const f32x4 z4 = {0.f, 0.f, 0.f, 0.f};
  f32x4 acc[4][4];
#pragma unroll
  for (int i = 0; i < 4; i++)
#pragma unroll
    for (int j = 0; j < 4; j++) acc[i][j] = z4;

  auto stage = [&](int buf, int k0){
#pragma unroll
    for (int is = 0; is < 2; ++is){
      const int rb = is * 64 + w * 16;
      const ushort* ga = Ab + (arow + rb + lr) * (long)lda + k0 + lc;
      const ushort* gb = Bb + (brow + rb + lr) * (long)ldb + k0 + lc;
      __builtin_amdgcn_global_load_lds((const __attribute__((address_space(1))) void*)ga,
                                       (__attribute__((address_space(3))) void*)&As[buf][rb * 32], 16, 0, 0);
      __builtin_amdgcn_global_load_lds((const __attribute__((address_space(1))) void*)gb,
                                       (__attribute__((address_space(3))) void*)&Bs[buf][rb * 32], 16, 0, 0);
    }
  };

  const int nk = K >> 5;
  stage(0, 0);
  for (int kt = 0; kt < nk; ++kt){
    __syncthreads();
    if (kt + 1 < nk) stage((kt + 1) & 1, (kt + 1) * 32);
    const int buf = kt & 1;
    short8x a[4], b[4];
#pragma unroll
    for (int i = 0; i < 4; i++){
      a[i] = *(const short8x*)&As[buf][(wm * 64 + i * 16 + lq) * 32 + q4 * 8];
      b[i] = *(const short8x*)&Bs[buf][(wn * 64 + i * 16 + lq) * 32 + q4 * 8];
    }
#pragma unroll
    for (int i = 0; i < 4; i++)
#pragma unroll
      for (int j = 0; j < 4; j++)
        acc[i][j] = __builtin_amdgcn_mfma_f32_16x16x32_bf16(a[i], b[j], acc[i][j], 0, 0, 0);
  }

  const long crowb = arow + wm * 64;
  const long ccolb = brow + wn * 64;
#pragma unroll
  for (int i = 0; i < 4; i++)
#pragma unroll
    for (int j = 0; j < 4; j++)
#pragma unroll
      for (int r = 0; r < 4; r++){
        const long row = crowb + i * 16 + q4 * 4 + r;
        const long col = ccolb + j * 16 + lq;
        const float v = acc[i][j][r] * scale;
        if (OUTBF) ((ushort*)Cv)[(long)z * cZ + row * ldc + col] = f2bf(v);
        else       ((float*)Cv)[(long)z * cZ + row * ldc + col] = v;
      }
}

// ---------------- flash attention v8: att[2] two-tile pipeline (T15) --------------------------
// 256 blocks (1/CU), 8 waves. xcd = blk&7 keeps all blocks of one (b,h) on one XCD (round-5
// verified L2 locality). Wave w owns q-rows [qb*256+w*32, +32); diag tile wd = qb*4 + (w>>1).
// Per step tt: {ds_read K(tt) -> exp2/pack of tile tt-1 (overlaps) -> one lgkm drain ->
// setprio(1): QK-MFMA(tt into st[tt&1]) + PV-MFMA(tt-1 from Vb[(tt-1)&3]) -> setprio(0)}.
// K double-buffered, V quad-buffered (stage (tt+2)&3 vs read (tt-1)&3: disjoint). Diagonal
// masking only in the drain step (tt == wd+1) or post-loop -> steady state has no mask code.
// q is read from the fused q|lat buffer (row stride 2560); exp2 with log2e folded into Wq.
__global__ __launch_bounds__(512, 2)
void flash8_kernel(const ushort* __restrict__ q, const ushort* __restrict__ k,
                   const ushort* __restrict__ vT, ushort* __restrict__ attnO)
{
  __shared__ __align__(16) ushort Kb[2][64 * 128];   // [t][d] swizzled granules, 16KB each
  __shared__ __align__(16) ushort Vb[4][128 * 64];   // [d][t] swizzled granules, 16KB each
  __shared__ __align__(16) ushort Pl[8][2][16][72];  // per-wave per-si P^T bounce

  const int tid = threadIdx.x, lane = tid & 63, w = tid >> 6;
  const int lq = lane & 15, q4 = lane >> 4;

  const int xcd = blockIdx.x & 7;
  const int bh = xcd * 4 + ((blockIdx.x >> 3) & 3);
  const int qb = blockIdx.x >> 5;
  const int b = bh & 1, h = bh >> 1;

  const int nt = (qb + 1) * 4;              // 64-wide t-tiles staged by this block
  const int wd = qb * 4 + (w >> 1);         // wave's diagonal tile
  const int moff = (w & 1) * 32;            // wave's row offset within the diag tile

  const ushort* kb_ = k + (long)b * 2048 * 2048 + h * 128;        // row t stride 2048
  const ushort* vb_ = vT + (long)h * 128 * 4096 + (long)b * 2048; // row d stride 4096

  // hoisted per-lane staging addresses (t0-independent parts)
  const ushort* kbase[2]; const ushort* vbase[2]; int kofs[2], vofs[2];
#pragma unroll
  for (int is = 0; is < 2; ++is){
    const int ofse = is * 4096 + w * 512;
    const int krow = (ofse >> 7) + (lane >> 4);            // 0..63
    const int kg = (lane & 15) ^ (krow & 7);
    kbase[is] = kb_ + (long)krow * 2048 + kg * 8;
    kofs[is] = ofse;
    const int drow = (ofse >> 6) + (lane >> 3);            // 0..127
    const int vg = (lane & 7) ^ (drow & 7);
    vbase[is] = vb_ + (long)drow * 4096 + vg * 8;
    vofs[is] = ofse;
  }

  auto stage = [&](int kbuf, int vbuf, int tt){
    const long t0 = (long)tt * 64;
#pragma unroll
    for (int is = 0; is < 2; ++is){
      __builtin_amdgcn_global_load_lds((const __attribute__((address_space(1))) void*)(kbase[is] + t0 * 2048),
          (__attribute__((address_space(3))) void*)&Kb[kbuf][kofs[is]], 16, 0, 0);
      __builtin_amdgcn_global_load_lds((const __attribute__((address_space(1))) void*)(vbase[is] + t0),
          (__attribute__((address_space(3))) void*)&Vb[vbuf][vofs[is]], 16, 0, 0);
    }
  };

  const f32x4 z4 = {0.f, 0.f, 0.f, 0.f};

  const int qrow0 = qb * 256 + w * 32;
  const long qgbase = (long)b * 2048 + qrow0;

  // Q B-frags from fused q|lat buffer (row stride 2560)
  short8x qf[2][4];
#pragma unroll
  for (int si = 0; si < 2; si++){
    const ushort* qp = q + (qgbase + si * 16 + lq) * 2560 + h * 128 + q4 * 8;
#pragma unroll
    for (int ks = 0; ks < 4; ks++) qf[si][ks] = *(const short8x*)(qp + ks * 32);
  }

  f32x4 oacc[8][2];
#pragma unroll
  for (int dt = 0; dt < 8; dt++){ oacc[dt][0] = z4; oacc[dt][1] = z4; }
  float dsum0 = 0.f, dsum1 = 0.f;
  f32x4 stA[4][2], stB[4][2];

  auto qk_load = [&](int cur, short8x (&ak)[4][4]){
#pragma unroll
    for (int ti = 0; ti < 4; ti++){
      const int r = ti * 16 + lq;
      const int rb = r * 128;
      const int rx = r & 7;
#pragma unroll
      for (int ks = 0; ks < 4; ks++)
        ak[ti][ks] = *(const short8x*)&Kb[cur][rb + (((ks * 4 + q4) ^ rx) * 8)];
    }
  };
  auto qk_mfma = [&](short8x (&ak)[4][4], f32x4 (&st)[4][2]){
#pragma unroll
    for (int ti = 0; ti < 4; ti++){ st[ti][0] = z4; st[ti][1] = z4; }
#pragma unroll
    for (int ks = 0; ks < 4; ks++)
#pragma unroll
      for (int ti = 0; ti < 4; ti++)
#pragma unroll
        for (int si = 0; si < 2; si++)
          st[ti][si] = __builtin_amdgcn_mfma_f32_16x16x32_bf16(ak[ti][ks], qf[si][ks], st[ti][si], 0, 0, 0);
  };
  auto fin_pack = [&](f32x4 (&st)[4][2], bool diag){
#pragma unroll
    for (int si = 0; si < 2; si++)
#pragma unroll
      for (int ti = 0; ti < 4; ti++){
        ushort4 pb;
#pragma unroll
        for (int r = 0; r < 4; r++){
          const int tl = ti * 16 + q4 * 4 + r;
          float p = exp2f(st[ti][si][r]);
          if (diag && tl > moff + si * 16 + lq) p = 0.f;
          if (si) dsum1 += p; else dsum0 += p;
          ((ushort*)&pb)[r] = f2bf(p);
        }
        *(ushort4*)&Pl[w][si][lq][ti * 16 + q4 * 4] = pb;
      }
  };
  auto fin_pv = [&](int vbuf){
#pragma unroll
    for (int si = 0; si < 2; si++){
      const short8x pf0 = *(const short8x*)&Pl[w][si][lq][q4 * 8];        // t = q4*8+j
      const short8x pf1 = *(const short8x*)&Pl[w][si][lq][32 + q4 * 8];   // t = 32+q4*8+j
#pragma unroll
      for (int dt = 0; dt < 8; dt++){
        const int r = dt * 16 + lq;
        const int rb = r * 64;
        const int rx = lq & 7;
        const short8x av0 = *(const short8x*)&Vb[vbuf][rb + (((q4) ^ rx) * 8)];
        const short8x av1 = *(const short8x*)&Vb[vbuf][rb + (((4 + q4) ^ rx) * 8)];
        oacc[dt][si] = __builtin_amdgcn_mfma_f32_16x16x32_bf16(av0, pf0, oacc[dt][si], 0, 0, 0);
        oacc[dt][si] = __builtin_amdgcn_mfma_f32_16x16x32_bf16(av1, pf1, oacc[dt][si], 0, 0, 0);
      }
    }
  };

  stage(0, 0, 0);
  stage(1, 1, 1);          // nt >= 4 always

#pragma unroll 1
  for (int tt = 0; tt < nt; ++tt){
    if (tt == nt - 1) asm volatile("s_waitcnt vmcnt(0)" ::: "memory");
    else              asm volatile("s_waitcnt vmcnt(4)" ::: "memory");
    __syncthreads();

    if (tt <= wd){
      short8x ak[4][4];
      qk_load(tt & 1, ak);
      if (tt == 0){
        qk_mfma(ak, stA);
      } else if (tt & 1){
        fin_pack(stA, false);
        asm volatile("s_waitcnt lgkmcnt(0)" ::: "memory");
        __builtin_amdgcn_sched_barrier(0);
        __builtin_amdgcn_s_setprio(1);
        qk_mfma(ak, stB);
        fin_pv((tt - 1) & 3);
        __builtin_amdgcn_s_setprio(0);
      } else {
        fin_pack(stB, false);
        asm volatile("s_waitcnt lgkmcnt(0)" ::: "memory");
        __builtin_amdgcn_sched_barrier(0);
        __builtin_amdgcn_s_setprio(1);
        qk_mfma(ak, stA);
        fin_pv((tt - 1) & 3);
        __builtin_amdgcn_s_setprio(0);
      }
    } else if (tt == wd + 1){
      if (wd & 1) fin_pack(stB, true); else fin_pack(stA, true);
      asm volatile("s_waitcnt lgkmcnt(0)" ::: "memory");
      __builtin_amdgcn_sched_barrier(0);
      fin_pv(wd & 3);
    }
    __syncthreads();                        // all reads of overwritten bufs complete
    if (tt + 2 < nt) stage(tt & 1, (tt + 2) & 3, tt + 2);
  }
  if (wd == nt - 1){                        // waves 6,7: diag tile finished post-loop
    fin_pack(stB, true);                    // nt-1 is odd -> stB
    asm volatile("s_waitcnt lgkmcnt(0)" ::: "memory");
    __builtin_amdgcn_sched_barrier(0);
    fin_pv(wd & 3);
  }

  dsum0 += __shfl_xor(dsum0, 16); dsum0 += __shfl_xor(dsum0, 32);
  dsum1 += __shfl_xor(dsum1, 16); dsum1 += __shfl_xor(dsum1, 32);
  const float inv0 = 1.f / dsum0, inv1 = 1.f / dsum1;

#pragma unroll
  for (int dt = 0; dt < 8; dt++)
#pragma unroll
    for (int si = 0; si < 2; si++){
      const float inv = si ? inv1 : inv0;
      ushort4 o;
      o.x = f2bf(oacc[dt][si][0] * inv);
      o.y = f2bf(oacc[dt][si][1] * inv);
      o.z = f2bf(oacc[dt][si][2] * inv);
      o.w = f2bf(oacc[dt][si][3] * inv);
      *(ushort4*)(attnO + (qgbase + si * 16 + lq) * 2048 + h * 128 + dt * 16 + q4 * 4) = o;
    }
}

// ---------------- host launcher ----------------
extern "C" void kernel_launch(void* const* d_in, const int* in_sizes, int n_in,
                              void* d_out, int out_size, void* d_ws, size_t ws_size,
                              hipStream_t stream)
{
  const float* x   = (const float*)d_in[0];
  const float* Wd  = (const float*)d_in[1];
  const float* Wuk = (const float*)d_in[2];
  const float* Wuv = (const float*)d_in[3];
  const float* Wq  = (const float*)d_in[4];
  const float* Wo  = (const float*)d_in[5];
  float* out = (float*)d_out;
  ushort* ws = (ushort*)d_ws;

  ushort* xb    = ws + 0L;          // [4096][2048]
  ushort* wqdb  = ws + 8388608L;    // [2560][2048]: rows 0..2047 = Wq*(log2e/sqrt(128)), 2048..2559 = Wd
  ushort* wob   = ws + 13631488L;   // [2048(m)][2048(h,d)]
  ushort* wukb  = ws + 17825792L;   // [2048(h,d)][512(c)]
  ushort* wuvb  = ws + 18874368L;   // [2048(h,d)][512(c)]
  ushort* qlat  = ws + 19922944L;   // [4096][2560]: cols 0..2047 = q (pre-scaled), 2048..2559 = lat
  ushort* kb    = ws + 30408704L;   // [4096(b,t)][2048(h,d)]
  ushort* vTb   = ws + 38797312L;   // [2048(h,d)][4096(b,t)]
  ushort* attnO = ws + 47185920L;   // [4096(b,s)][2048(h,d)]

  // log2(e)/sqrt(128): folded into Wq so flash uses exp2 (identical softmax)
  const float QSCL = 0.12751744800f;

  cvt_kernel<<<8192, 256, 0, stream>>>(x,   xb,            8388608L, 1.0f);
  cvt_kernel<<<4096, 256, 0, stream>>>(Wq,  wqdb,          4194304L, QSCL);
  cvt_kernel<<<1024, 256, 0, stream>>>(Wd,  wqdb + 4194304L, 1048576L, 1.0f);
  cvt_kernel<<<4096, 256, 0, stream>>>(Wo,  wob,           4194304L, 1.0f);
  cvt_kernel<<<1024, 256, 0, stream>>>(Wuk, wukb,          1048576L, 1.0f);
  cvt_kernel<<<1024, 256, 0, stream>>>(Wuv, wuvb,          1048576L, 1.0f);

  // fused q|lat = x @ [Wq' | Wd]^T : [4096, 2560]
  gemm_bt<1><<<dim3(20, 32, 1), 256, 0, stream>>>(xb, wqdb, qlat, 4096, 2560, 2048,
      2048, 2048, 2560, 0L, 0L, 0L, 1.0f);
  // k = lat @ Wuk^T : [4096, 2048]   (lat = qlat cols 2048.., lda 2560)
  gemm_bt<1><<<dim3(16, 32, 1), 256, 0, stream>>>(qlat + 2048, wukb, kb, 4096, 2048, 512,
      2560, 512, 2048, 0L, 0L, 0L, 1.0f);
  // vT = Wuv @ lat^T : [2048(h,d)][4096(b,t)]
  gemm_bt<1><<<dim3(32, 16, 1), 256, 0, stream>>>(wuvb, qlat + 2048, vTb, 2048, 4096, 512,
      512, 2560, 4096, 0L, 0L, 0L, 1.0f);
  // flash attention (causal, d=128): attnO [4096][2048]
  flash8_kernel<<<256, 512, 0, stream>>>(qlat, kb, vTb, attnO);
  // out = attnO @ Wo^T : fp32 [4096, 2048]
  gemm_bt<0><<<dim3(16, 32, 1), 256, 0, stream>>>(attnO, wob, out, 4096, 2048, 2048,
      2048, 2048, 2048, 0L, 0L, 0L, 1.0f);
}

// Round 9
// 411.844 us; speedup vs baseline: 1.3601x; 1.3601x over previous
//
#include <hip/hip_runtime.h>
#include <hip/hip_bf16.h>

typedef __attribute__((ext_vector_type(8))) short short8x;   // 8 x bf16 (4 VGPR) MFMA A/B frag
typedef __attribute__((ext_vector_type(4))) float f32x4;     // MFMA C/D frag

__device__ __forceinline__ ushort f2bf(float f){
  union { __hip_bfloat16 b; ushort u; } cvt;
  cvt.b = __float2bfloat16(f);                // RNE
  return cvt.u;
}

// ---------------- elementwise fp32 -> bf16 (optional scale) ----------------
__global__ __launch_bounds__(256) void cvt_kernel(const float* __restrict__ in, ushort* __restrict__ out,
                                                  long n, float scale){
  long i = ((long)blockIdx.x * 256 + threadIdx.x) * 4;
  if (i >= n) return;
  float4 v = *(const float4*)(in + i);
  ushort4 o;
  o.x = f2bf(v.x * scale); o.y = f2bf(v.y * scale); o.z = f2bf(v.z * scale); o.w = f2bf(v.w * scale);
  *(ushort4*)(out + i) = o;
}

// ---------------- generic bf16 GEMM: C = A[M,K] * B  with B given as BT[N,K] ----------------
// 128x128 tile, BK=32, 4 waves (2x2), double-buffered LDS staged via global_load_lds(16B).
// XCD-aware block swizzle (T1): all launches have (gridDim.x*gridDim.y) % 8 == 0.
template<int OUTBF>
__global__ __launch_bounds__(256, 3)
void gemm_bt(const ushort* __restrict__ A, const ushort* __restrict__ BT, void* __restrict__ Cv,
             int M, int N, int K, int lda, int ldb, int ldc,
             long aZ, long bZ, long cZ, float scale)
{
  __shared__ __align__(16) ushort As[2][128 * 32];
  __shared__ __align__(16) ushort Bs[2][128 * 32];
  const int z = blockIdx.z;
  const ushort* Ab = A + (long)z * aZ;
  const ushort* Bb = BT + (long)z * bZ;
  const int tid = threadIdx.x, lane = tid & 63, w = tid >> 6;
  const int wm = w >> 1, wn = w & 1;
  const int lq = lane & 15, q4 = lane >> 4;

  int lin = blockIdx.x + gridDim.x * blockIdx.y;
  const int cpx = (gridDim.x * gridDim.y) >> 3;
  lin = (lin & 7) * cpx + (lin >> 3);
  const int bx = lin % gridDim.x, by = lin / gridDim.x;

  const long arow = (long)by * 128, brow = (long)bx * 128;
  const int lr = lane >> 2, lc = (lane & 3) * 8;

  const f32x4 z4 = {0.f, 0.f, 0.f, 0.f};
  f32x4 acc[4][4];
#pragma unroll
  for (int i = 0; i < 4; i++)
#pragma unroll
    for (int j = 0; j < 4; j++) acc[i][j] = z4;

  auto stage = [&](int buf, int k0){
#pragma unroll
    for (int is = 0; is < 2; ++is){
      const int rb = is * 64 + w * 16;
      const ushort* ga = Ab + (arow + rb + lr) * (long)lda + k0 + lc;
      const ushort* gb = Bb + (brow + rb + lr) * (long)ldb + k0 + lc;
      __builtin_amdgcn_global_load_lds((const __attribute__((address_space(1))) void*)ga,
                                       (__attribute__((address_space(3))) void*)&As[buf][rb * 32], 16, 0, 0);
      __builtin_amdgcn_global_load_lds((const __attribute__((address_space(1))) void*)gb,
                                       (__attribute__((address_space(3))) void*)&Bs[buf][rb * 32], 16, 0, 0);
    }
  };

  const int nk = K >> 5;
  stage(0, 0);
  for (int kt = 0; kt < nk; ++kt){
    __syncthreads();
    if (kt + 1 < nk) stage((kt + 1) & 1, (kt + 1) * 32);
    const int buf = kt & 1;
    short8x a[4], b[4];
#pragma unroll
    for (int i = 0; i < 4; i++){
      a[i] = *(const short8x*)&As[buf][(wm * 64 + i * 16 + lq) * 32 + q4 * 8];
      b[i] = *(const short8x*)&Bs[buf][(wn * 64 + i * 16 + lq) * 32 + q4 * 8];
    }
#pragma unroll
    for (int i = 0; i < 4; i++)
#pragma unroll
      for (int j = 0; j < 4; j++)
        acc[i][j] = __builtin_amdgcn_mfma_f32_16x16x32_bf16(a[i], b[j], acc[i][j], 0, 0, 0);
  }

  const long crowb = arow + wm * 64;
  const long ccolb = brow + wn * 64;
#pragma unroll
  for (int i = 0; i < 4; i++)
#pragma unroll
    for (int j = 0; j < 4; j++)
#pragma unroll
      for (int r = 0; r < 4; r++){
        const long row = crowb + i * 16 + q4 * 4 + r;
        const long col = ccolb + j * 16 + lq;
        const float v = acc[i][j][r] * scale;
        if (OUTBF) ((ushort*)Cv)[(long)z * cZ + row * ldc + col] = f2bf(v);
        else       ((float*)Cv)[(long)z * cZ + row * ldc + col] = v;
      }
}

// ---------------- flash attention v9: att[2] two-tile pipeline, register-budgeted -----------
// flash8 structure with the spill fixed: __launch_bounds__(512,1) (VGPR cap 256) and K A-frags
// loaded per-ti inside the QK loop (16 VGPR live instead of 64). 256 blocks (1/CU), 8 waves.
// Per step tt: {exp2/pack(tile tt-1) overlaps ds_read K(tt) -> one lgkm drain ->
// setprio(1): QK-MFMA(tt) + PV-MFMA(tt-1) -> setprio(0)}. K dbuf, V quad-buf.
// Diagonal masking only in the drain step. q from fused q|lat (stride 2560), exp2-folded Wq.
__global__ __launch_bounds__(512, 1)
void flash9_kernel(const ushort* __restrict__ q, const ushort* __restrict__ k,
                   const ushort* __restrict__ vT, ushort* __restrict__ attnO)
{
  __shared__ __align__(16) ushort Kb[2][64 * 128];   // [t][d] swizzled granules, 16KB each
  __shared__ __align__(16) ushort Vb[4][128 * 64];   // [d][t] swizzled granules, 16KB each
  __shared__ __align__(16) ushort Pl[8][2][16][72];  // per-wave per-si P^T bounce

  const int tid = threadIdx.x, lane = tid & 63, w = tid >> 6;
  const int lq = lane & 15, q4 = lane >> 4;

  const int xcd = blockIdx.x & 7;
  const int bh = xcd * 4 + ((blockIdx.x >> 3) & 3);
  const int qb = blockIdx.x >> 5;
  const int b = bh & 1, h = bh >> 1;

  const int nt = (qb + 1) * 4;              // 64-wide t-tiles staged by this block
  const int wd = qb * 4 + (w >> 1);         // wave's diagonal tile
  const int moff = (w & 1) * 32;            // wave's row offset within the diag tile

  const ushort* kb_ = k + (long)b * 2048 * 2048 + h * 128;        // row t stride 2048
  const ushort* vb_ = vT + (long)h * 128 * 4096 + (long)b * 2048; // row d stride 4096

  // hoisted per-lane staging addresses (t0-independent parts)
  const ushort* kbase[2]; const ushort* vbase[2]; int kofs[2], vofs[2];
#pragma unroll
  for (int is = 0; is < 2; ++is){
    const int ofse = is * 4096 + w * 512;
    const int krow = (ofse >> 7) + (lane >> 4);            // 0..63
    const int kg = (lane & 15) ^ (krow & 7);
    kbase[is] = kb_ + (long)krow * 2048 + kg * 8;
    kofs[is] = ofse;
    const int drow = (ofse >> 6) + (lane >> 3);            // 0..127
    const int vg = (lane & 7) ^ (drow & 7);
    vbase[is] = vb_ + (long)drow * 4096 + vg * 8;
    vofs[is] = ofse;
  }

  auto stage = [&](int kbuf, int vbuf, int tt){
    const long t0 = (long)tt * 64;
#pragma unroll
    for (int is = 0; is < 2; ++is){
      __builtin_amdgcn_global_load_lds((const __attribute__((address_space(1))) void*)(kbase[is] + t0 * 2048),
          (__attribute__((address_space(3))) void*)&Kb[kbuf][kofs[is]], 16, 0, 0);
      __builtin_amdgcn_global_load_lds((const __attribute__((address_space(1))) void*)(vbase[is] + t0),
          (__attribute__((address_space(3))) void*)&Vb[vbuf][vofs[is]], 16, 0, 0);
    }
  };

  const f32x4 z4 = {0.f, 0.f, 0.f, 0.f};

  const int qrow0 = qb * 256 + w * 32;
  const long qgbase = (long)b * 2048 + qrow0;

  // Q B-frags from fused q|lat buffer (row stride 2560)
  short8x qf[2][4];
#pragma unroll
  for (int si = 0; si < 2; si++){
    const ushort* qp = q + (qgbase + si * 16 + lq) * 2560 + h * 128 + q4 * 8;
#pragma unroll
    for (int ks = 0; ks < 4; ks++) qf[si][ks] = *(const short8x*)(qp + ks * 32);
  }

  f32x4 oacc[8][2];
#pragma unroll
  for (int dt = 0; dt < 8; dt++){ oacc[dt][0] = z4; oacc[dt][1] = z4; }
  float dsum0 = 0.f, dsum1 = 0.f;
  f32x4 stA[4][2], stB[4][2];

  // QK: per-ti frag load (16 VGPR live) then 8 MFMAs into st[ti][*]
  auto qk_mfma = [&](int cur, f32x4 (&st)[4][2]){
#pragma unroll
    for (int ti = 0; ti < 4; ti++){
      const int r = ti * 16 + lq;
      const int rb = r * 128;
      const int rx = r & 7;
      short8x a0 = *(const short8x*)&Kb[cur][rb + (((0 + q4) ^ rx) * 8)];
      short8x a1 = *(const short8x*)&Kb[cur][rb + (((4 + q4) ^ rx) * 8)];
      short8x a2 = *(const short8x*)&Kb[cur][rb + (((8 + q4) ^ rx) * 8)];
      short8x a3 = *(const short8x*)&Kb[cur][rb + (((12 + q4) ^ rx) * 8)];
      st[ti][0] = __builtin_amdgcn_mfma_f32_16x16x32_bf16(a0, qf[0][0], z4, 0, 0, 0);
      st[ti][1] = __builtin_amdgcn_mfma_f32_16x16x32_bf16(a0, qf[1][0], z4, 0, 0, 0);
      st[ti][0] = __builtin_amdgcn_mfma_f32_16x16x32_bf16(a1, qf[0][1], st[ti][0], 0, 0, 0);
      st[ti][1] = __builtin_amdgcn_mfma_f32_16x16x32_bf16(a1, qf[1][1], st[ti][1], 0, 0, 0);
      st[ti][0] = __builtin_amdgcn_mfma_f32_16x16x32_bf16(a2, qf[0][2], st[ti][0], 0, 0, 0);
      st[ti][1] = __builtin_amdgcn_mfma_f32_16x16x32_bf16(a2, qf[1][2], st[ti][1], 0, 0, 0);
      st[ti][0] = __builtin_amdgcn_mfma_f32_16x16x32_bf16(a3, qf[0][3], st[ti][0], 0, 0, 0);
      st[ti][1] = __builtin_amdgcn_mfma_f32_16x16x32_bf16(a3, qf[1][3], st[ti][1], 0, 0, 0);
    }
  };
  auto fin_pack = [&](f32x4 (&st)[4][2], bool diag){
#pragma unroll
    for (int si = 0; si < 2; si++)
#pragma unroll
      for (int ti = 0; ti < 4; ti++){
        ushort4 pb;
#pragma unroll
        for (int r = 0; r < 4; r++){
          const int tl = ti * 16 + q4 * 4 + r;
          float p = exp2f(st[ti][si][r]);
          if (diag && tl > moff + si * 16 + lq) p = 0.f;
          if (si) dsum1 += p; else dsum0 += p;
          ((ushort*)&pb)[r] = f2bf(p);
        }
        *(ushort4*)&Pl[w][si][lq][ti * 16 + q4 * 4] = pb;
      }
  };
  auto fin_pv = [&](int vbuf){
#pragma unroll
    for (int si = 0; si < 2; si++){
      const short8x pf0 = *(const short8x*)&Pl[w][si][lq][q4 * 8];        // t = q4*8+j
      const short8x pf1 = *(const short8x*)&Pl[w][si][lq][32 + q4 * 8];   // t = 32+q4*8+j
#pragma unroll
      for (int dt = 0; dt < 8; dt++){
        const int r = dt * 16 + lq;
        const int rb = r * 64;
        const int rx = lq & 7;
        const short8x av0 = *(const short8x*)&Vb[vbuf][rb + (((q4) ^ rx) * 8)];
        const short8x av1 = *(const short8x*)&Vb[vbuf][rb + (((4 + q4) ^ rx) * 8)];
        oacc[dt][si] = __builtin_amdgcn_mfma_f32_16x16x32_bf16(av0, pf0, oacc[dt][si], 0, 0, 0);
        oacc[dt][si] = __builtin_amdgcn_mfma_f32_16x16x32_bf16(av1, pf1, oacc[dt][si], 0, 0, 0);
      }
    }
  };

  stage(0, 0, 0);
  stage(1, 1, 1);          // nt >= 4 always

#pragma unroll 1
  for (int tt = 0; tt < nt; ++tt){
    if (tt == nt - 1) asm volatile("s_waitcnt vmcnt(0)" ::: "memory");
    else              asm volatile("s_waitcnt vmcnt(4)" ::: "memory");
    __syncthreads();

    if (tt <= wd){
      if (tt == 0){
        qk_mfma(0, stA);
      } else if (tt & 1){
        fin_pack(stA, false);
        asm volatile("s_waitcnt lgkmcnt(0)" ::: "memory");
        __builtin_amdgcn_sched_barrier(0);
        __builtin_amdgcn_s_setprio(1);
        qk_mfma(tt & 1, stB);
        fin_pv((tt - 1) & 3);
        __builtin_amdgcn_s_setprio(0);
      } else {
        fin_pack(stB, false);
        asm volatile("s_waitcnt lgkmcnt(0)" ::: "memory");
        __builtin_amdgcn_sched_barrier(0);
        __builtin_amdgcn_s_setprio(1);
        qk_mfma(tt & 1, stA);
        fin_pv((tt - 1) & 3);
        __builtin_amdgcn_s_setprio(0);
      }
    } else if (tt == wd + 1){
      if (wd & 1) fin_pack(stB, true); else fin_pack(stA, true);
      asm volatile("s_waitcnt lgkmcnt(0)" ::: "memory");
      __builtin_amdgcn_sched_barrier(0);
      fin_pv(wd & 3);
    }
    __syncthreads();                        // all reads of overwritten bufs complete
    if (tt + 2 < nt) stage(tt & 1, (tt + 2) & 3, tt + 2);
  }
  if (wd == nt - 1){                        // waves 6,7: diag tile finished post-loop
    fin_pack(stB, true);                    // nt-1 is odd -> stB
    asm volatile("s_waitcnt lgkmcnt(0)" ::: "memory");
    __builtin_amdgcn_sched_barrier(0);
    fin_pv(wd & 3);
  }

  dsum0 += __shfl_xor(dsum0, 16); dsum0 += __shfl_xor(dsum0, 32);
  dsum1 += __shfl_xor(dsum1, 16); dsum1 += __shfl_xor(dsum1, 32);
  const float inv0 = 1.f / dsum0, inv1 = 1.f / dsum1;

#pragma unroll
  for (int dt = 0; dt < 8; dt++)
#pragma unroll
    for (int si = 0; si < 2; si++){
      const float inv = si ? inv1 : inv0;
      ushort4 o;
      o.x = f2bf(oacc[dt][si][0] * inv);
      o.y = f2bf(oacc[dt][si][1] * inv);
      o.z = f2bf(oacc[dt][si][2] * inv);
      o.w = f2bf(oacc[dt][si][3] * inv);
      *(ushort4*)(attnO + (qgbase + si * 16 + lq) * 2048 + h * 128 + dt * 16 + q4 * 4) = o;
    }
}

// ---------------- host launcher ----------------
extern "C" void kernel_launch(void* const* d_in, const int* in_sizes, int n_in,
                              void* d_out, int out_size, void* d_ws, size_t ws_size,
                              hipStream_t stream)
{
  const float* x   = (const float*)d_in[0];
  const float* Wd  = (const float*)d_in[1];
  const float* Wuk = (const float*)d_in[2];
  const float* Wuv = (const float*)d_in[3];
  const float* Wq  = (const float*)d_in[4];
  const float* Wo  = (const float*)d_in[5];
  float* out = (float*)d_out;
  ushort* ws = (ushort*)d_ws;

  ushort* xb    = ws + 0L;          // [4096][2048]
  ushort* wqdb  = ws + 8388608L;    // [2560][2048]: rows 0..2047 = Wq*(log2e/sqrt(128)), 2048..2559 = Wd
  ushort* wob   = ws + 13631488L;   // [2048(m)][2048(h,d)]
  ushort* wukb  = ws + 17825792L;   // [2048(h,d)][512(c)]
  ushort* wuvb  = ws + 18874368L;   // [2048(h,d)][512(c)]
  ushort* qlat  = ws + 19922944L;   // [4096][2560]: cols 0..2047 = q (pre-scaled), 2048..2559 = lat
  ushort* kb    = ws + 30408704L;   // [4096(b,t)][2048(h,d)]
  ushort* vTb   = ws + 38797312L;   // [2048(h,d)][4096(b,t)]
  ushort* attnO = ws + 47185920L;   // [4096(b,s)][2048(h,d)]

  // log2(e)/sqrt(128): folded into Wq so flash uses exp2 (identical softmax)
  const float QSCL = 0.12751744800f;

  cvt_kernel<<<8192, 256, 0, stream>>>(x,   xb,            8388608L, 1.0f);
  cvt_kernel<<<4096, 256, 0, stream>>>(Wq,  wqdb,          4194304L, QSCL);
  cvt_kernel<<<1024, 256, 0, stream>>>(Wd,  wqdb + 4194304L, 1048576L, 1.0f);
  cvt_kernel<<<4096, 256, 0, stream>>>(Wo,  wob,           4194304L, 1.0f);
  cvt_kernel<<<1024, 256, 0, stream>>>(Wuk, wukb,          1048576L, 1.0f);
  cvt_kernel<<<1024, 256, 0, stream>>>(Wuv, wuvb,          1048576L, 1.0f);

  // fused q|lat = x @ [Wq' | Wd]^T : [4096, 2560]
  gemm_bt<1><<<dim3(20, 32, 1), 256, 0, stream>>>(xb, wqdb, qlat, 4096, 2560, 2048,
      2048, 2048, 2560, 0L, 0L, 0L, 1.0f);
  // k = lat @ Wuk^T : [4096, 2048]   (lat = qlat cols 2048.., lda 2560)
  gemm_bt<1><<<dim3(16, 32, 1), 256, 0, stream>>>(qlat + 2048, wukb, kb, 4096, 2048, 512,
      2560, 512, 2048, 0L, 0L, 0L, 1.0f);
  // vT = Wuv @ lat^T : [2048(h,d)][4096(b,t)]
  gemm_bt<1><<<dim3(32, 16, 1), 256, 0, stream>>>(wuvb, qlat + 2048, vTb, 2048, 4096, 512,
      512, 2560, 4096, 0L, 0L, 0L, 1.0f);
  // flash attention (causal, d=128): attnO [4096][2048]
  flash9_kernel<<<256, 512, 0, stream>>>(qlat, kb, vTb, attnO);
  // out = attnO @ Wo^T : fp32 [4096, 2048]
  gemm_bt<0><<<dim3(16, 32, 1), 256, 0, stream>>>(attnO, wob, out, 4096, 2048, 2048,
      2048, 2048, 2048, 0L, 0L, 0L, 1.0f);
}

// Round 10
// 271.644 us; speedup vs baseline: 2.0620x; 1.5161x over previous
//
#include <hip/hip_runtime.h>
#include <hip/hip_bf16.h>

typedef __attribute__((ext_vector_type(8))) short short8x;   // 8 x bf16 (4 VGPR) MFMA A/B frag
typedef __attribute__((ext_vector_type(4))) float f32x4;     // MFMA C/D frag

__device__ __forceinline__ ushort f2bf(float f){
  union { __hip_bfloat16 b; ushort u; } cvt;
  cvt.b = __float2bfloat16(f);                // RNE
  return cvt.u;
}

// ---------------- elementwise fp32 -> bf16 (optional scale) ----------------
__global__ __launch_bounds__(256) void cvt_kernel(const float* __restrict__ in, ushort* __restrict__ out,
                                                  long n, float scale){
  long i = ((long)blockIdx.x * 256 + threadIdx.x) * 4;
  if (i >= n) return;
  float4 v = *(const float4*)(in + i);
  ushort4 o;
  o.x = f2bf(v.x * scale); o.y = f2bf(v.y * scale); o.z = f2bf(v.z * scale); o.w = f2bf(v.w * scale);
  *(ushort4*)(out + i) = o;
}

// ---------------- generic bf16 GEMM: C = A[M,K] * B  with B given as BT[N,K] ----------------
// 128x128 tile, BK=32, 4 waves (2x2), double-buffered LDS staged via global_load_lds(16B).
// XCD-aware block swizzle (T1): all launches have (gridDim.x*gridDim.y) % 8 == 0.
template<int OUTBF>
__global__ __launch_bounds__(256, 3)
void gemm_bt(const ushort* __restrict__ A, const ushort* __restrict__ BT, void* __restrict__ Cv,
             int M, int N, int K, int lda, int ldb, int ldc,
             long aZ, long bZ, long cZ, float scale)
{
  __shared__ __align__(16) ushort As[2][128 * 32];
  __shared__ __align__(16) ushort Bs[2][128 * 32];
  const int z = blockIdx.z;
  const ushort* Ab = A + (long)z * aZ;
  const ushort* Bb = BT + (long)z * bZ;
  const int tid = threadIdx.x, lane = tid & 63, w = tid >> 6;
  const int wm = w >> 1, wn = w & 1;
  const int lq = lane & 15, q4 = lane >> 4;

  int lin = blockIdx.x + gridDim.x * blockIdx.y;
  const int cpx = (gridDim.x * gridDim.y) >> 3;
  lin = (lin & 7) * cpx + (lin >> 3);
  const int bx = lin % gridDim.x, by = lin / gridDim.x;

  const long arow = (long)by * 128, brow = (long)bx * 128;
  const int lr = lane >> 2, lc = (lane & 3) * 8;

  const f32x4 z4 = {0.f, 0.f, 0.f, 0.f};
  f32x4 acc[4][4];
#pragma unroll
  for (int i = 0; i < 4; i++)
#pragma unroll
    for (int j = 0; j < 4; j++) acc[i][j] = z4;

  auto stage = [&](int buf, int k0){
#pragma unroll
    for (int is = 0; is < 2; ++is){
      const int rb = is * 64 + w * 16;
      const ushort* ga = Ab + (arow + rb + lr) * (long)lda + k0 + lc;
      const ushort* gb = Bb + (brow + rb + lr) * (long)ldb + k0 + lc;
      __builtin_amdgcn_global_load_lds((const __attribute__((address_space(1))) void*)ga,
                                       (__attribute__((address_space(3))) void*)&As[buf][rb * 32], 16, 0, 0);
      __builtin_amdgcn_global_load_lds((const __attribute__((address_space(1))) void*)gb,
                                       (__attribute__((address_space(3))) void*)&Bs[buf][rb * 32], 16, 0, 0);
    }
  };

  const int nk = K >> 5;
  stage(0, 0);
  for (int kt = 0; kt < nk; ++kt){
    __syncthreads();
    if (kt + 1 < nk) stage((kt + 1) & 1, (kt + 1) * 32);
    const int buf = kt & 1;
    short8x a[4], b[4];
#pragma unroll
    for (int i = 0; i < 4; i++){
      a[i] = *(const short8x*)&As[buf][(wm * 64 + i * 16 + lq) * 32 + q4 * 8];
      b[i] = *(const short8x*)&Bs[buf][(wn * 64 + i * 16 + lq) * 32 + q4 * 8];
    }
#pragma unroll
    for (int i = 0; i < 4; i++)
#pragma unroll
      for (int j = 0; j < 4; j++)
        acc[i][j] = __builtin_amdgcn_mfma_f32_16x16x32_bf16(a[i], b[j], acc[i][j], 0, 0, 0);
  }

  const long crowb = arow + wm * 64;
  const long ccolb = brow + wn * 64;
#pragma unroll
  for (int i = 0; i < 4; i++)
#pragma unroll
    for (int j = 0; j < 4; j++)
#pragma unroll
      for (int r = 0; r < 4; r++){
        const long row = crowb + i * 16 + q4 * 4 + r;
        const long col = ccolb + j * 16 + lq;
        const float v = acc[i][j][r] * scale;
        if (OUTBF) ((ushort*)Cv)[(long)z * cZ + row * ldc + col] = f2bf(v);
        else       ((float*)Cv)[(long)z * cZ + row * ldc + col] = v;
      }
}

// ---------------- flash attention v10: 4 waves, 64 q-rows/wave, KVBLK=64 --------------------
// 256 blocks = 32 bh (XCD-local via blk&7, round-5-verified L2 locality) x 8 q-strips of 256.
// Wave w owns 64 q-rows (4 si sub-blocks of 16); Q held in registers (qf[4][4], 64 VGPR).
// Arithmetic intensity doubled vs flash7: per step/wave 128 MFMA vs K16+V32+P8 LDS b128 reads
// -> LDS pipe (~1900cyc/CU/step) ~ matches MFMA pipe; 4 independent si chains give in-wave ILP.
// Depth-2 staging, counted vmcnt(8); K/V granule^(row&7) swizzle; single-base staging addrs
// (is-offsets compile-time; XOR swizzle is is-invariant). Diag mask only on wave's diag tile.
// q from fused q|lat buffer (stride 2560), exp2 with log2e/sqrt(128) folded into Wq.
__global__ __launch_bounds__(256, 1)
void flash10_kernel(const ushort* __restrict__ q, const ushort* __restrict__ k,
                    const ushort* __restrict__ vT, ushort* __restrict__ attnO)
{
  __shared__ __align__(16) ushort Kb[2][64 * 128];   // [t][d] swizzled granules, 16KB each
  __shared__ __align__(16) ushort Vb[2][128 * 64];   // [d][t] swizzled granules, 16KB each
  __shared__ __align__(16) ushort Pl[4][4][16][72];  // [w][si][s-local][t-local+pad], 36KB

  const int tid = threadIdx.x, lane = tid & 63, w = tid >> 6;   // w = 0..3
  const int lq = lane & 15, q4 = lane >> 4;

  const int xcd = blockIdx.x & 7;
  const int bh = xcd * 4 + ((blockIdx.x >> 3) & 3);
  const int qb = blockIdx.x >> 5;           // 0..7 strip of 256 q-rows
  const int b = bh & 1, h = bh >> 1;

  const int nt = (qb + 1) * 4;              // 64-wide t-tiles staged by this block
  const int wdiag = qb * 4 + w;             // wave's diagonal tile

  const ushort* kb_ = k + (long)b * 2048 * 2048 + h * 128;        // row t stride 2048
  const ushort* vb_ = vT + (long)h * 128 * 4096 + (long)b * 2048; // row d stride 4096

  // single-base staging addresses; per-issue offsets are compile-time (swizzle is is-invariant)
  const int krow0 = w * 4 + (lane >> 4);                          // is adds 16
  const int kg = (lane & 15) ^ (krow0 & 7);
  const ushort* kbase = kb_ + (long)krow0 * 2048 + kg * 8;
  const int kofs0 = w * 512;                                      // is adds 2048

  const int drow0 = w * 8 + (lane >> 3);                          // is adds 32
  const int vg = (lane & 7) ^ (drow0 & 7);
  const ushort* vbase = vb_ + (long)drow0 * 4096 + vg * 8;
  const int vofs0 = w * 512;

  auto stage = [&](int buf, int tt){
    const ushort* kp = kbase + (long)tt * 64 * 2048;
    const ushort* vp = vbase + (long)tt * 64;
#pragma unroll
    for (int is = 0; is < 4; ++is){
      __builtin_amdgcn_global_load_lds((const __attribute__((address_space(1))) void*)(kp + (long)is * 16 * 2048),
          (__attribute__((address_space(3))) void*)&Kb[buf][kofs0 + is * 2048], 16, 0, 0);
      __builtin_amdgcn_global_load_lds((const __attribute__((address_space(1))) void*)(vp + (long)is * 32 * 4096),
          (__attribute__((address_space(3))) void*)&Vb[buf][vofs0 + is * 2048], 16, 0, 0);
    }
  };

  const f32x4 z4 = {0.f, 0.f, 0.f, 0.f};

  const int qrow0 = qb * 256 + w * 64;
  const long qgbase = (long)b * 2048 + qrow0;

  // Q B-frags from fused q|lat buffer (row stride 2560): s = qrow0+si*16+lq, d = ks*32+q4*8+j
  short8x qf[4][4];
#pragma unroll
  for (int si = 0; si < 4; si++){
    const ushort* qp = q + (qgbase + si * 16 + lq) * 2560 + h * 128 + q4 * 8;
#pragma unroll
    for (int ks = 0; ks < 4; ks++) qf[si][ks] = *(const short8x*)(qp + ks * 32);
  }

  f32x4 oacc[8][4];                          // [dt][si]  O^T[d][s]
#pragma unroll
  for (int dt = 0; dt < 8; dt++)
#pragma unroll
    for (int si = 0; si < 4; si++) oacc[dt][si] = z4;
  float dsum[4] = {0.f, 0.f, 0.f, 0.f};

  stage(0, 0);
  stage(1, 1);          // nt >= 4 always

#pragma unroll 1
  for (int tt = 0; tt < nt; ++tt){
    if (tt == nt - 1) asm volatile("s_waitcnt vmcnt(0)" ::: "memory");
    else              asm volatile("s_waitcnt vmcnt(8)" ::: "memory");
    __syncthreads();
    const int cur = tt & 1;

    if (tt <= wdiag){
      const bool diag = (tt == wdiag);
      // QK + exp2 + pack, streamed per ti (st transient = 4 VGPR per si)
#pragma unroll
      for (int ti = 0; ti < 4; ++ti){
        const int r = ti * 16 + lq;
        const int rb = r * 128;
        const int rx = r & 7;
        const short8x a0 = *(const short8x*)&Kb[cur][rb + (((q4) ^ rx) * 8)];
        const short8x a1 = *(const short8x*)&Kb[cur][rb + (((4 + q4) ^ rx) * 8)];
        const short8x a2 = *(const short8x*)&Kb[cur][rb + (((8 + q4) ^ rx) * 8)];
        const short8x a3 = *(const short8x*)&Kb[cur][rb + (((12 + q4) ^ rx) * 8)];
#pragma unroll
        for (int si = 0; si < 4; ++si){
          f32x4 st = __builtin_amdgcn_mfma_f32_16x16x32_bf16(a0, qf[si][0], z4, 0, 0, 0);
          st = __builtin_amdgcn_mfma_f32_16x16x32_bf16(a1, qf[si][1], st, 0, 0, 0);
          st = __builtin_amdgcn_mfma_f32_16x16x32_bf16(a2, qf[si][2], st, 0, 0, 0);
          st = __builtin_amdgcn_mfma_f32_16x16x32_bf16(a3, qf[si][3], st, 0, 0, 0);
          ushort4 pb;
#pragma unroll
          for (int r4 = 0; r4 < 4; ++r4){
            const int tl = ti * 16 + q4 * 4 + r4;
            float p = exp2f(st[r4]);
            if (diag && tl > si * 16 + lq) p = 0.f;
            dsum[si] += p;
            ((ushort*)&pb)[r4] = f2bf(p);
          }
          *(ushort4*)&Pl[w][si][lq][ti * 16 + q4 * 4] = pb;
        }
      }
      asm volatile("s_waitcnt lgkmcnt(0)" ::: "memory");
      __builtin_amdgcn_sched_barrier(0);
      // PV in si-pairs: V frags read once per pair (pf = 16 VGPR live)
#pragma unroll
      for (int sp = 0; sp < 2; ++sp){
        const short8x pf00 = *(const short8x*)&Pl[w][2 * sp][lq][q4 * 8];
        const short8x pf01 = *(const short8x*)&Pl[w][2 * sp][lq][32 + q4 * 8];
        const short8x pf10 = *(const short8x*)&Pl[w][2 * sp + 1][lq][q4 * 8];
        const short8x pf11 = *(const short8x*)&Pl[w][2 * sp + 1][lq][32 + q4 * 8];
#pragma unroll
        for (int dt = 0; dt < 8; ++dt){
          const int r = dt * 16 + lq;
          const int rb = r * 64;
          const int rx = lq & 7;
          const short8x av0 = *(const short8x*)&Vb[cur][rb + (((q4) ^ rx) * 8)];
          const short8x av1 = *(const short8x*)&Vb[cur][rb + (((4 + q4) ^ rx) * 8)];
          oacc[dt][2 * sp]     = __builtin_amdgcn_mfma_f32_16x16x32_bf16(av0, pf00, oacc[dt][2 * sp], 0, 0, 0);
          oacc[dt][2 * sp]     = __builtin_amdgcn_mfma_f32_16x16x32_bf16(av1, pf01, oacc[dt][2 * sp], 0, 0, 0);
          oacc[dt][2 * sp + 1] = __builtin_amdgcn_mfma_f32_16x16x32_bf16(av0, pf10, oacc[dt][2 * sp + 1], 0, 0, 0);
          oacc[dt][2 * sp + 1] = __builtin_amdgcn_mfma_f32_16x16x32_bf16(av1, pf11, oacc[dt][2 * sp + 1], 0, 0, 0);
        }
      }
    }
    __syncthreads();                        // all reads of buf[cur] complete
    if (tt + 2 < nt) stage(cur, tt + 2);    // overwrite buf[cur] = buf[(tt+2)&1]
  }

  float inv[4];
#pragma unroll
  for (int si = 0; si < 4; ++si){
    float d = dsum[si];
    d += __shfl_xor(d, 16);
    d += __shfl_xor(d, 32);
    inv[si] = 1.f / d;
  }

#pragma unroll
  for (int dt = 0; dt < 8; dt++)
#pragma unroll
    for (int si = 0; si < 4; si++){
      ushort4 o;
      o.x = f2bf(oacc[dt][si][0] * inv[si]);
      o.y = f2bf(oacc[dt][si][1] * inv[si]);
      o.z = f2bf(oacc[dt][si][2] * inv[si]);
      o.w = f2bf(oacc[dt][si][3] * inv[si]);
      *(ushort4*)(attnO + (qgbase + si * 16 + lq) * 2048 + h * 128 + dt * 16 + q4 * 4) = o;
    }
}

// ---------------- host launcher ----------------
extern "C" void kernel_launch(void* const* d_in, const int* in_sizes, int n_in,
                              void* d_out, int out_size, void* d_ws, size_t ws_size,
                              hipStream_t stream)
{
  const float* x   = (const float*)d_in[0];
  const float* Wd  = (const float*)d_in[1];
  const float* Wuk = (const float*)d_in[2];
  const float* Wuv = (const float*)d_in[3];
  const float* Wq  = (const float*)d_in[4];
  const float* Wo  = (const float*)d_in[5];
  float* out = (float*)d_out;
  ushort* ws = (ushort*)d_ws;

  ushort* xb    = ws + 0L;          // [4096][2048]
  ushort* wqdb  = ws + 8388608L;    // [2560][2048]: rows 0..2047 = Wq*(log2e/sqrt(128)), 2048..2559 = Wd
  ushort* wob   = ws + 13631488L;   // [2048(m)][2048(h,d)]
  ushort* wukb  = ws + 17825792L;   // [2048(h,d)][512(c)]
  ushort* wuvb  = ws + 18874368L;   // [2048(h,d)][512(c)]
  ushort* qlat  = ws + 19922944L;   // [4096][2560]: cols 0..2047 = q (pre-scaled), 2048..2559 = lat
  ushort* kb    = ws + 30408704L;   // [4096(b,t)][2048(h,d)]
  ushort* vTb   = ws + 38797312L;   // [2048(h,d)][4096(b,t)]
  ushort* attnO = ws + 47185920L;   // [4096(b,s)][2048(h,d)]

  // log2(e)/sqrt(128): folded into Wq so flash uses exp2 (identical softmax)
  const float QSCL = 0.12751744800f;

  cvt_kernel<<<8192, 256, 0, stream>>>(x,   xb,            8388608L, 1.0f);
  cvt_kernel<<<4096, 256, 0, stream>>>(Wq,  wqdb,          4194304L, QSCL);
  cvt_kernel<<<1024, 256, 0, stream>>>(Wd,  wqdb + 4194304L, 1048576L, 1.0f);
  cvt_kernel<<<4096, 256, 0, stream>>>(Wo,  wob,           4194304L, 1.0f);
  cvt_kernel<<<1024, 256, 0, stream>>>(Wuk, wukb,          1048576L, 1.0f);
  cvt_kernel<<<1024, 256, 0, stream>>>(Wuv, wuvb,          1048576L, 1.0f);

  // fused q|lat = x @ [Wq' | Wd]^T : [4096, 2560]
  gemm_bt<1><<<dim3(20, 32, 1), 256, 0, stream>>>(xb, wqdb, qlat, 4096, 2560, 2048,
      2048, 2048, 2560, 0L, 0L, 0L, 1.0f);
  // k = lat @ Wuk^T : [4096, 2048]   (lat = qlat cols 2048.., lda 2560)
  gemm_bt<1><<<dim3(16, 32, 1), 256, 0, stream>>>(qlat + 2048, wukb, kb, 4096, 2048, 512,
      2560, 512, 2048, 0L, 0L, 0L, 1.0f);
  // vT = Wuv @ lat^T : [2048(h,d)][4096(b,t)]
  gemm_bt<1><<<dim3(32, 16, 1), 256, 0, stream>>>(wuvb, qlat + 2048, vTb, 2048, 4096, 512,
      512, 2560, 4096, 0L, 0L, 0L, 1.0f);
  // flash attention (causal, d=128): attnO [4096][2048]
  flash10_kernel<<<256, 256, 0, stream>>>(qlat, kb, vTb, attnO);
  // out = attnO @ Wo^T : fp32 [4096, 2048]
  gemm_bt<0><<<dim3(16, 32, 1), 256, 0, stream>>>(attnO, wob, out, 4096, 2048, 2048,
      2048, 2048, 2048, 0L, 0L, 0L, 1.0f);
}

// Round 12
// 237.806 us; speedup vs baseline: 2.3554x; 1.1423x over previous
//
#include <hip/hip_runtime.h>
#include <hip/hip_bf16.h>

typedef __attribute__((ext_vector_type(8))) short short8x;   // 8 x bf16 (4 VGPR) MFMA A/B frag
typedef __attribute__((ext_vector_type(4))) float f32x4;     // MFMA C/D frag

__device__ __forceinline__ ushort f2bf(float f){
  union { __hip_bfloat16 b; ushort u; } cvt;
  cvt.b = __float2bfloat16(f);                // RNE
  return cvt.u;
}

// ---------------- elementwise fp32 -> bf16 (optional scale) ----------------
__global__ __launch_bounds__(256) void cvt_kernel(const float* __restrict__ in, ushort* __restrict__ out,
                                                  long n, float scale){
  long i = ((long)blockIdx.x * 256 + threadIdx.x) * 4;
  if (i >= n) return;
  float4 v = *(const float4*)(in + i);
  ushort4 o;
  o.x = f2bf(v.x * scale); o.y = f2bf(v.y * scale); o.z = f2bf(v.z * scale); o.w = f2bf(v.w * scale);
  *(ushort4*)(out + i) = o;
}

// ---------------- generic bf16 GEMM: C = A[M,K] * B  with B given as BT[N,K] ----------------
// 128x128 tile, BK=32, 4 waves (2x2), double-buffered LDS staged via global_load_lds(16B).
// XCD-aware block swizzle (T1): all launches have (gridDim.x*gridDim.y) % 8 == 0.
template<int OUTBF>
__global__ __launch_bounds__(256, 3)
void gemm_bt(const ushort* __restrict__ A, const ushort* __restrict__ BT, void* __restrict__ Cv,
             int M, int N, int K, int lda, int ldb, int ldc,
             long aZ, long bZ, long cZ, float scale)
{
  __shared__ __align__(16) ushort As[2][128 * 32];
  __shared__ __align__(16) ushort Bs[2][128 * 32];
  const int z = blockIdx.z;
  const ushort* Ab = A + (long)z * aZ;
  const ushort* Bb = BT + (long)z * bZ;
  const int tid = threadIdx.x, lane = tid & 63, w = tid >> 6;
  const int wm = w >> 1, wn = w & 1;
  const int lq = lane & 15, q4 = lane >> 4;

  int lin = blockIdx.x + gridDim.x * blockIdx.y;
  const int cpx = (gridDim.x * gridDim.y) >> 3;
  lin = (lin & 7) * cpx + (lin >> 3);
  const int bx = lin % gridDim.x, by = lin / gridDim.x;

  const long arow = (long)by * 128, brow = (long)bx * 128;
  const int lr = lane >> 2, lc = (lane & 3) * 8;

  const f32x4 z4 = {0.f, 0.f, 0.f, 0.f};
  f32x4 acc[4][4];
#pragma unroll
  for (int i = 0; i < 4; i++)
#pragma unroll
    for (int j = 0; j < 4; j++) acc[i][j] = z4;

  auto stage = [&](int buf, int k0){
#pragma unroll
    for (int is = 0; is < 2; ++is){
      const int rb = is * 64 + w * 16;
      const ushort* ga = Ab + (arow + rb + lr) * (long)lda + k0 + lc;
      const ushort* gb = Bb + (brow + rb + lr) * (long)ldb + k0 + lc;
      __builtin_amdgcn_global_load_lds((const __attribute__((address_space(1))) void*)ga,
                                       (__attribute__((address_space(3))) void*)&As[buf][rb * 32], 16, 0, 0);
      __builtin_amdgcn_global_load_lds((const __attribute__((address_space(1))) void*)gb,
                                       (__attribute__((address_space(3))) void*)&Bs[buf][rb * 32], 16, 0, 0);
    }
  };

  const int nk = K >> 5;
  stage(0, 0);
  for (int kt = 0; kt < nk; ++kt){
    __syncthreads();
    if (kt + 1 < nk) stage((kt + 1) & 1, (kt + 1) * 32);
    const int buf = kt & 1;
    short8x a[4], b[4];
#pragma unroll
    for (int i = 0; i < 4; i++){
      a[i] = *(const short8x*)&As[buf][(wm * 64 + i * 16 + lq) * 32 + q4 * 8];
      b[i] = *(const short8x*)&Bs[buf][(wn * 64 + i * 16 + lq) * 32 + q4 * 8];
    }
#pragma unroll
    for (int i = 0; i < 4; i++)
#pragma unroll
      for (int j = 0; j < 4; j++)
        acc[i][j] = __builtin_amdgcn_mfma_f32_16x16x32_bf16(a[i], b[j], acc[i][j], 0, 0, 0);
  }

  const long crowb = arow + wm * 64;
  const long ccolb = brow + wn * 64;
#pragma unroll
  for (int i = 0; i < 4; i++)
#pragma unroll
    for (int j = 0; j < 4; j++)
#pragma unroll
      for (int r = 0; r < 4; r++){
        const long row = crowb + i * 16 + q4 * 4 + r;
        const long col = ccolb + j * 16 + lq;
        const float v = acc[i][j][r] * scale;
        if (OUTBF) ((ushort*)Cv)[(long)z * cZ + row * ldc + col] = f2bf(v);
        else       ((float*)Cv)[(long)z * cZ + row * ldc + col] = v;
      }
}

// ---------------- flash attention v12: 4 waves x 32 q-rows, KVBLK=64, 2 blocks/CU -----------
// v11 with the Pl overflow fixed: Pl last dim must cover t=0..63. Instead of stride 72 (18KB,
// would push LDS to 82KB > 80KB budget), Pl is stride-64 with a 16B-granule XOR swizzle
// (G' = G ^ (lq&7), same XOR on write and read -> bijective per row, banks uniform). LDS
// total exactly 80KB -> 2 independent blocks/CU co-resident; their waves interleave without
// shared barriers, hiding each other's vmcnt/barrier stalls.
// 512 blocks: i<256 primaries take heavy strips {15..8} (dispatched first), i>=256 take {0..7}.
// bh = (i&7)*4 + ((i>>3)&3) keeps each (b,h) on one XCD (round-5-verified FETCH 146->24.6MB).
// dt-outer PV shares each V fragment across both si chains. Depth-2 staging, counted vmcnt(8).
// q from fused q|lat buffer (stride 2560), exp2 with log2e/sqrt(128) folded into Wq.
__global__ __launch_bounds__(256, 1)
void flash12_kernel(const ushort* __restrict__ q, const ushort* __restrict__ k,
                    const ushort* __restrict__ vT, ushort* __restrict__ attnO)
{
  __shared__ __align__(16) ushort Kb[2][64 * 128];   // [t][d] swizzled granules, 16KB each
  __shared__ __align__(16) ushort Vb[2][128 * 64];   // [d][t] swizzled granules, 16KB each
  __shared__ __align__(16) ushort Pl[4][2][16][64];  // [w][si][s][t], granule-XOR swizzled, 16KB

  const int tid = threadIdx.x, lane = tid & 63, w = tid >> 6;   // w = 0..3
  const int lq = lane & 15, q4 = lane >> 4;

  const int i = blockIdx.x;
  const int pr = i >> 8;                     // 0 = primary (heavy), 1 = secondary (light)
  const int ii = i & 255;
  const int xcd = ii & 7;
  const int bh = xcd * 4 + ((ii >> 3) & 3);
  const int j = ii >> 5;                     // 0..7
  const int strip = pr ? j : (15 - j);       // strips of 128 q-rows
  const int b = bh & 1, h = bh >> 1;

  const int nt = 2 * (strip + 1);            // 64-wide t-tiles staged by this block
  const int wdiag = strip * 2 + (w >> 1);    // wave's diagonal tile
  const int moff = (w & 1) * 32;             // wave's row offset within diag tile

  const ushort* kb_ = k + (long)b * 2048 * 2048 + h * 128;        // row t stride 2048
  const ushort* vb_ = vT + (long)h * 128 * 4096 + (long)b * 2048; // row d stride 4096

  // single-base staging addresses; per-issue offsets compile-time (swizzle is is-invariant)
  const int krow0 = w * 4 + (lane >> 4);                          // is adds 16
  const int kg = (lane & 15) ^ (krow0 & 7);
  const ushort* kbase = kb_ + (long)krow0 * 2048 + kg * 8;
  const int kofs0 = w * 512;                                      // is adds 2048

  const int drow0 = w * 8 + (lane >> 3);                          // is adds 32
  const int vg = (lane & 7) ^ (drow0 & 7);
  const ushort* vbase = vb_ + (long)drow0 * 4096 + vg * 8;
  const int vofs0 = w * 512;

  auto stage = [&](int buf, int tt){
    const ushort* kp = kbase + (long)tt * 64 * 2048;
    const ushort* vp = vbase + (long)tt * 64;
#pragma unroll
    for (int is = 0; is < 4; ++is){
      __builtin_amdgcn_global_load_lds((const __attribute__((address_space(1))) void*)(kp + (long)is * 16 * 2048),
          (__attribute__((address_space(3))) void*)&Kb[buf][kofs0 + is * 2048], 16, 0, 0);
      __builtin_amdgcn_global_load_lds((const __attribute__((address_space(1))) void*)(vp + (long)is * 32 * 4096),
          (__attribute__((address_space(3))) void*)&Vb[buf][vofs0 + is * 2048], 16, 0, 0);
    }
  };

  const f32x4 z4 = {0.f, 0.f, 0.f, 0.f};

  const int qrow0 = strip * 128 + w * 32;
  const long qgbase = (long)b * 2048 + qrow0;

  // Q B-frags from fused q|lat buffer (row stride 2560): s = qrow0+si*16+lq, d = ks*32+q4*8+j
  short8x qf[2][4];
#pragma unroll
  for (int si = 0; si < 2; si++){
    const ushort* qp = q + (qgbase + si * 16 + lq) * 2560 + h * 128 + q4 * 8;
#pragma unroll
    for (int ks = 0; ks < 4; ks++) qf[si][ks] = *(const short8x*)(qp + ks * 32);
  }

  f32x4 oacc[8][2];                          // [dt][si]  O^T[d][s]
#pragma unroll
  for (int dt = 0; dt < 8; dt++){ oacc[dt][0] = z4; oacc[dt][1] = z4; }
  float dsum[2] = {0.f, 0.f};

  const int prx = lq & 7;                    // Pl granule XOR key (per s-row)

  stage(0, 0);
  stage(1, 1);          // nt >= 2 always

#pragma unroll 1
  for (int tt = 0; tt < nt; ++tt){
    if (tt == nt - 1) asm volatile("s_waitcnt vmcnt(0)" ::: "memory");
    else              asm volatile("s_waitcnt vmcnt(8)" ::: "memory");
    __syncthreads();
    const int cur = tt & 1;

    if (tt <= wdiag){
      const bool diag = (tt == wdiag);
      // QK + exp2 + pack, streamed per ti; Pl write at swizzled granule
#pragma unroll
      for (int ti = 0; ti < 4; ++ti){
        const int r = ti * 16 + lq;
        const int rb = r * 128;
        const int rx = r & 7;
        const short8x a0 = *(const short8x*)&Kb[cur][rb + (((q4) ^ rx) * 8)];
        const short8x a1 = *(const short8x*)&Kb[cur][rb + (((4 + q4) ^ rx) * 8)];
        const short8x a2 = *(const short8x*)&Kb[cur][rb + (((8 + q4) ^ rx) * 8)];
        const short8x a3 = *(const short8x*)&Kb[cur][rb + (((12 + q4) ^ rx) * 8)];
        const int cG = (ti * 2 + (q4 >> 1)) ^ prx;          // 16B-granule index, swizzled
        const int pco = cG * 8 + (q4 & 1) * 4;              // elem offset within row
#pragma unroll
        for (int si = 0; si < 2; ++si){
          f32x4 st = __builtin_amdgcn_mfma_f32_16x16x32_bf16(a0, qf[si][0], z4, 0, 0, 0);
          st = __builtin_amdgcn_mfma_f32_16x16x32_bf16(a1, qf[si][1], st, 0, 0, 0);
          st = __builtin_amdgcn_mfma_f32_16x16x32_bf16(a2, qf[si][2], st, 0, 0, 0);
          st = __builtin_amdgcn_mfma_f32_16x16x32_bf16(a3, qf[si][3], st, 0, 0, 0);
          ushort4 pb;
#pragma unroll
          for (int r4 = 0; r4 < 4; ++r4){
            const int tl = ti * 16 + q4 * 4 + r4;
            float p = exp2f(st[r4]);
            if (diag && tl > moff + si * 16 + lq) p = 0.f;
            dsum[si] += p;
            ((ushort*)&pb)[r4] = f2bf(p);
          }
          *(ushort4*)&Pl[w][si][lq][pco] = pb;
        }
      }
      asm volatile("s_waitcnt lgkmcnt(0)" ::: "memory");
      __builtin_amdgcn_sched_barrier(0);
      // PV, dt-outer: P frags at swizzled granules; V frags read once, shared by both si
      const short8x pf00 = *(const short8x*)&Pl[w][0][lq][(q4 ^ prx) * 8];
      const short8x pf01 = *(const short8x*)&Pl[w][0][lq][((4 + q4) ^ prx) * 8];
      const short8x pf10 = *(const short8x*)&Pl[w][1][lq][(q4 ^ prx) * 8];
      const short8x pf11 = *(const short8x*)&Pl[w][1][lq][((4 + q4) ^ prx) * 8];
      __builtin_amdgcn_sched_barrier(0);
#pragma unroll
      for (int dt = 0; dt < 8; ++dt){
        const int r = dt * 16 + lq;
        const int rb = r * 64;
        const int rx = lq & 7;
        const short8x av0 = *(const short8x*)&Vb[cur][rb + (((q4) ^ rx) * 8)];
        const short8x av1 = *(const short8x*)&Vb[cur][rb + (((4 + q4) ^ rx) * 8)];
        oacc[dt][0] = __builtin_amdgcn_mfma_f32_16x16x32_bf16(av0, pf00, oacc[dt][0], 0, 0, 0);
        oacc[dt][0] = __builtin_amdgcn_mfma_f32_16x16x32_bf16(av1, pf01, oacc[dt][0], 0, 0, 0);
        oacc[dt][1] = __builtin_amdgcn_mfma_f32_16x16x32_bf16(av0, pf10, oacc[dt][1], 0, 0, 0);
        oacc[dt][1] = __builtin_amdgcn_mfma_f32_16x16x32_bf16(av1, pf11, oacc[dt][1], 0, 0, 0);
      }
    }
    __syncthreads();                        // all reads of buf[cur] complete
    if (tt + 2 < nt) stage(cur, tt + 2);    // overwrite buf[cur] = buf[(tt+2)&1]
  }

  float inv[2];
#pragma unroll
  for (int si = 0; si < 2; ++si){
    float d = dsum[si];
    d += __shfl_xor(d, 16);
    d += __shfl_xor(d, 32);
    inv[si] = 1.f / d;
  }

#pragma unroll
  for (int dt = 0; dt < 8; dt++)
#pragma unroll
    for (int si = 0; si < 2; si++){
      ushort4 o;
      o.x = f2bf(oacc[dt][si][0] * inv[si]);
      o.y = f2bf(oacc[dt][si][1] * inv[si]);
      o.z = f2bf(oacc[dt][si][2] * inv[si]);
      o.w = f2bf(oacc[dt][si][3] * inv[si]);
      *(ushort4*)(attnO + (qgbase + si * 16 + lq) * 2048 + h * 128 + dt * 16 + q4 * 4) = o;
    }
}

// ---------------- host launcher ----------------
extern "C" void kernel_launch(void* const* d_in, const int* in_sizes, int n_in,
                              void* d_out, int out_size, void* d_ws, size_t ws_size,
                              hipStream_t stream)
{
  const float* x   = (const float*)d_in[0];
  const float* Wd  = (const float*)d_in[1];
  const float* Wuk = (const float*)d_in[2];
  const float* Wuv = (const float*)d_in[3];
  const float* Wq  = (const float*)d_in[4];
  const float* Wo  = (const float*)d_in[5];
  float* out = (float*)d_out;
  ushort* ws = (ushort*)d_ws;

  ushort* xb    = ws + 0L;          // [4096][2048]
  ushort* wqdb  = ws + 8388608L;    // [2560][2048]: rows 0..2047 = Wq*(log2e/sqrt(128)), 2048..2559 = Wd
  ushort* wob   = ws + 13631488L;   // [2048(m)][2048(h,d)]
  ushort* wukb  = ws + 17825792L;   // [2048(h,d)][512(c)]
  ushort* wuvb  = ws + 18874368L;   // [2048(h,d)][512(c)]
  ushort* qlat  = ws + 19922944L;   // [4096][2560]: cols 0..2047 = q (pre-scaled), 2048..2559 = lat
  ushort* kb    = ws + 30408704L;   // [4096(b,t)][2048(h,d)]
  ushort* vTb   = ws + 38797312L;   // [2048(h,d)][4096(b,t)]
  ushort* attnO = ws + 47185920L;   // [4096(b,s)][2048(h,d)]

  // log2(e)/sqrt(128): folded into Wq so flash uses exp2 (identical softmax)
  const float QSCL = 0.12751744800f;

  cvt_kernel<<<8192, 256, 0, stream>>>(x,   xb,            8388608L, 1.0f);
  cvt_kernel<<<4096, 256, 0, stream>>>(Wq,  wqdb,          4194304L, QSCL);
  cvt_kernel<<<1024, 256, 0, stream>>>(Wd,  wqdb + 4194304L, 1048576L, 1.0f);
  cvt_kernel<<<4096, 256, 0, stream>>>(Wo,  wob,           4194304L, 1.0f);
  cvt_kernel<<<1024, 256, 0, stream>>>(Wuk, wukb,          1048576L, 1.0f);
  cvt_kernel<<<1024, 256, 0, stream>>>(Wuv, wuvb,          1048576L, 1.0f);

  // fused q|lat = x @ [Wq' | Wd]^T : [4096, 2560]
  gemm_bt<1><<<dim3(20, 32, 1), 256, 0, stream>>>(xb, wqdb, qlat, 4096, 2560, 2048,
      2048, 2048, 2560, 0L, 0L, 0L, 1.0f);
  // k = lat @ Wuk^T : [4096, 2048]   (lat = qlat cols 2048.., lda 2560)
  gemm_bt<1><<<dim3(16, 32, 1), 256, 0, stream>>>(qlat + 2048, wukb, kb, 4096, 2048, 512,
      2560, 512, 2048, 0L, 0L, 0L, 1.0f);
  // vT = Wuv @ lat^T : [2048(h,d)][4096(b,t)]
  gemm_bt<1><<<dim3(32, 16, 1), 256, 0, stream>>>(wuvb, qlat + 2048, vTb, 2048, 4096, 512,
      512, 2560, 4096, 0L, 0L, 0L, 1.0f);
  // flash attention (causal, d=128): attnO [4096][2048]
  flash12_kernel<<<512, 256, 0, stream>>>(qlat, kb, vTb, attnO);
  // out = attnO @ Wo^T : fp32 [4096, 2048]
  gemm_bt<0><<<dim3(16, 32, 1), 256, 0, stream>>>(attnO, wob, out, 4096, 2048, 2048,
      2048, 2048, 2048, 0L, 0L, 0L, 1.0f);
}